// Round 8
// baseline (326.170 us; speedup 1.0000x reference)
//
#include <hip/hip_runtime.h>
#include <hip/hip_fp16.h>
#include <cmath>

#define BATCH 16
#define NID   15
#define NSEG  240
#define HW    262144          // 512*512
#define HEADB 65536
#define NSPL  4               // hist blocks per segment
#define S1T   512             // hist block threads
#define PREBLK 2048           // pre blocks (128 per batch, 2048 px each)
#define PSTRIDE 112           // floats per pre-block partial record (105 stats + 1 bg + pad)

// compact key space for d = exp(-arg) in [0,1]:
//   d >= 2^-8 : fine buckets (float_bits>>15), 2305 keys, ~0.39% relative width
//   d <  2^-8 : exponent-only buckets (float_bits>>23), 119 keys
#define KFINEBASE 30208       // 0x3B800000 >> 15
#define KOVF 119
#define KTOT 2424             // 119 + 2305

__device__ __forceinline__ int keyof(float d) {
  unsigned b = __float_as_uint(d);
  return (b >= 0x3B800000u) ? (int)((b >> 15) - KFINEBASE + KOVF) : (int)(b >> 23);
}
__device__ __forceinline__ void boundsof(int k, float* lo, float* hi) {
  if (k >= KOVF) {
    unsigned u = (unsigned)(k - KOVF + KFINEBASE) << 15;
    *lo = __uint_as_float(u);
    *hi = __uint_as_float(u + 32768u);
  } else {
    *lo = __uint_as_float((unsigned)k << 23);
    *hi = __uint_as_float((unsigned)(k + 1) << 23);
  }
}

// fast transcendentals (ex/ey round to half afterwards; sd quantized to u8)
__device__ __forceinline__ float fast_tanh(float x) {
  float e = __expf(2.0f * x);
  return 1.0f - 2.0f / (e + 1.0f);
}
__device__ __forceinline__ float fast_sigmoid(float x) {
  return 1.0f / (1.0f + __expf(-x));
}

struct Params { float cx, cy, e0, e1, var, valid, cnt; };
__device__ __forceinline__ Params calc_params(const float* __restrict__ st) {
  Params p;
  float cnt = st[0];
  float safe = fmaxf(cnt, 1.0f);
  p.cx = st[1] / safe;
  p.cy = st[2] / safe;
  float m0 = st[3] / safe, m1 = st[4] / safe;
  float v0 = st[5] - 2.0f * m0 * (m0 * safe) + m0 * m0 * cnt;
  float v1 = st[6] - 2.0f * m1 * (m1 * safe) + m1 * m1 * cnt;
  p.var = (v0 + v1) / (2.0f * safe);
  p.e0 = expf(10.0f * m0);
  p.e1 = expf(10.0f * m1);
  p.valid = (cnt > 0.f) ? 1.f : 0.f;
  p.cnt = cnt;
  return p;
}

// process one 4-px group: transform, pack-store, LDS stat atomics; returns bg contribution
__device__ __forceinline__ float process4(
    float4 v0, float4 v1, float4 v2, float4 v3, float4 v4, int4 t4, int4 l4,
    int g, size_t bq, float* __restrict__ lsp,
    unsigned* __restrict__ exyh, unsigned* __restrict__ tb8, unsigned* __restrict__ sd8) {
  float p0a[4] = {v0.x, v0.y, v0.z, v0.w};
  float p1a[4] = {v1.x, v1.y, v1.z, v1.w};
  float p2a[4] = {v2.x, v2.y, v2.z, v2.w};
  float p3a[4] = {v3.x, v3.y, v3.z, v3.w};
  float p4a[4] = {v4.x, v4.y, v4.z, v4.w};
  int ta[4] = {t4.x, t4.y, t4.z, t4.w};
  int la[4] = {l4.x, l4.y, l4.z, l4.w};
  unsigned eo[4], tpack = 0, spack = 0;
  float bg = 0.f;
  int px0 = g * 4;
#pragma unroll
  for (int k = 0; k < 4; ++k) {
    int px = px0 + k;
    float xm = (float)(px & 511) * (1.0f / 511.0f);
    float ym = (float)(px >> 9) * (1.0f / 511.0f);
    float ex = fast_tanh(p0a[k]) + xm;
    float ey = fast_tanh(p1a[k]) + ym;
    float sd = fast_sigmoid(p4a[k]);
    __half2 h = __floats2half2_rn(ex, ey);
    eo[k] = *reinterpret_cast<unsigned*>(&h);
    int t = ta[k];
    tpack |= ((unsigned)(t & 255)) << (8 * k);
    unsigned sq = (unsigned)(sd * 255.0f + 0.5f);
    spack |= (sq & 255u) << (8 * k);
    if (t >= 1 && t <= NID) {
      float* s = lsp + (t - 1) * 7;
      atomicAdd(s + 0, 1.0f);
      atomicAdd(s + 1, ex);
      atomicAdd(s + 2, ey);
      atomicAdd(s + 3, p2a[k]);
      atomicAdd(s + 4, p3a[k]);
      atomicAdd(s + 5, p2a[k] * p2a[k]);
      atomicAdd(s + 6, p3a[k] * p3a[k]);
    }
    if (la[k] == 0) bg += sd * sd;
  }
  ((uint4*)exyh)[bq + g] = make_uint4(eo[0], eo[1], eo[2], eo[3]);
  tb8[bq + g] = tpack;
  sd8[bq + g] = spack;
  return bg;
}

// ---------------- pre: all loads issued up-front (14 x 16B per thread) ----------------
__global__ void __launch_bounds__(256, 2)
pre_kernel(const float* __restrict__ pred, const int* __restrict__ inst,
           const int* __restrict__ lab, float* __restrict__ blockpart,
           unsigned* __restrict__ exyh, unsigned* __restrict__ tb8,
           unsigned* __restrict__ sd8) {
  __shared__ float ls[4][8][NID * 7];   // per-wave, 8-way lane-privatized
  __shared__ float lbg[4];
  int tid = threadIdx.x;
  int w = tid >> 6, lane = tid & 63, c8 = lane & 7;
  for (int i = tid; i < 4 * 8 * NID * 7; i += 256) ((float*)ls)[i] = 0.f;
  __syncthreads();
  int gid = blockIdx.x;
  int b = gid >> 7, c = gid & 127;      // 128 blocks per batch, 2048 px per block
  const float* pb = pred + (size_t)b * 5 * HW;
  const int4* ip = (const int4*)(inst + (size_t)b * HW);
  const int4* lp = (const int4*)(lab + (size_t)b * HW);
  size_t bq = (size_t)b * (HW / 4);
  int g0 = c * 512 + tid;               // two independent 4-px groups per thread
  int g1 = g0 + 256;
  // issue all 14 loads back-to-back (needs ~56 VGPRs of payload; launch_bounds allows it)
  float4 a0 = ((const float4*)pb)[g0];
  float4 a1 = ((const float4*)(pb + HW))[g0];
  float4 a2 = ((const float4*)(pb + 2 * HW))[g0];
  float4 a3 = ((const float4*)(pb + 3 * HW))[g0];
  float4 a4 = ((const float4*)(pb + 4 * HW))[g0];
  float4 b0 = ((const float4*)pb)[g1];
  float4 b1 = ((const float4*)(pb + HW))[g1];
  float4 b2 = ((const float4*)(pb + 2 * HW))[g1];
  float4 b3 = ((const float4*)(pb + 3 * HW))[g1];
  float4 b4 = ((const float4*)(pb + 4 * HW))[g1];
  int4 at = ip[g0];
  int4 al = lp[g0];
  int4 bt = ip[g1];
  int4 bl = lp[g1];
  float* lsp = ls[w][c8];
  float bgacc = process4(a0, a1, a2, a3, a4, at, al, g0, bq, lsp, exyh, tb8, sd8);
  bgacc += process4(b0, b1, b2, b3, b4, bt, bl, g1, bq, lsp, exyh, tb8, sd8);
  for (int off = 32; off > 0; off >>= 1) bgacc += __shfl_down(bgacc, off, 64);
  if (lane == 0) lbg[w] = bgacc;
  __syncthreads();
  float* bp = blockpart + (size_t)gid * PSTRIDE;
  for (int i = tid; i < NID * 7; i += 256) {
    float v = 0.f;
#pragma unroll
    for (int ww = 0; ww < 4; ++ww)
#pragma unroll
      for (int cc = 0; cc < 8; ++cc) v += ls[ww][cc][i];
    bp[i] = v;
  }
  if (tid == 0) bp[NID * 7] = lbg[0] + lbg[1] + lbg[2] + lbg[3];
}

// ---------------- reduce pre partials -> stats, seedbg ----------------
__global__ void reduce_kernel(const float* __restrict__ blockpart, float* __restrict__ stats,
                              float* __restrict__ seedbg) {
  int s = blockIdx.x;       // 0..105
  int b = blockIdx.y;
  int tid = threadIdx.x;    // 64; 128 blocks per batch -> 2 each
  float v = blockpart[(size_t)(b * 128 + tid) * PSTRIDE + s]
          + blockpart[(size_t)(b * 128 + 64 + tid) * PSTRIDE + s];
  for (int off = 32; off > 0; off >>= 1) v += __shfl_down(v, off, 64);
  if (tid == 0) {
    if (s < NID * 7) {
      int id = s / 7, st = s % 7;
      stats[(b * NID + id) * 8 + st] = v;
    } else {
      seedbg[b] = v;
    }
  }
}

// ---------------- phase 1: split per-segment LDS histograms from packed records ----------------
__global__ void __launch_bounds__(S1T, 4)
hist_kernel(const unsigned* __restrict__ exyh, const unsigned* __restrict__ tb8,
            const unsigned* __restrict__ sd8, const float* __restrict__ stats,
            unsigned short* __restrict__ partP, unsigned short* __restrict__ partN,
            float* __restrict__ seedi) {
  int bid = blockIdx.x;
  int seg = bid / NSPL, split = bid % NSPL;
  int b = seg / NID, n = seg % NID;
  __shared__ int histP[KTOT];
  __shared__ int histN[KTOT];
  __shared__ float prm[8];
  int tid = threadIdx.x;
  if (tid == 0) {
    Params pp = calc_params(stats + (size_t)seg * 8);
    prm[0] = pp.cx; prm[1] = pp.cy; prm[2] = pp.e0; prm[3] = pp.e1;
    prm[4] = pp.valid;
  }
  for (int k = tid; k < KTOT; k += S1T) { histP[k] = 0; histN[k] = 0; }
  __syncthreads();
  if (prm[4] == 0.f) return;   // invalid segment: partials never read
  float cx = prm[0], cy = prm[1], e0 = prm[2], e1 = prm[3];
  const uint4* ev = (const uint4*)exyh + (size_t)b * (HW / 4);
  const unsigned* tv = tb8 + (size_t)b * (HW / 4);
  const unsigned* sv = sd8 + (size_t)b * (HW / 4);
  int lane = tid & 63;
  int wid = tid >> 6;               // 8 waves
  int swl = (lane * 21) & 63;       // decorrelate bucket keys within a wave
  float sacc = 0.f;
  // 4-px groups: HW/4 = 65536 per batch; per split 16384; per block 32 iters of 512
  int g = split * 16384 + wid * 64 + swl;
  uint4 ee = ev[g];
  unsigned tp = tv[g];
  unsigned sp = sv[g];
  for (int it = 0; it < 32; ++it) {
    uint4 ne; unsigned ntp, nsp;
    int ng = g + 512;
    if (it < 31) { ne = ev[ng]; ntp = tv[ng]; nsp = sv[ng]; }
    unsigned ew[4] = {ee.x, ee.y, ee.z, ee.w};
#pragma unroll
    for (int k = 0; k < 4; ++k) {
      unsigned u = ew[k];
      __half2 h = *reinterpret_cast<__half2*>(&u);
      float2 e = __half22float2(h);
      float dx = e.x - cx;
      float dy = e.y - cy;
      float d = __expf(-(e0 * dx * dx + e1 * dy * dy));
      int key = keyof(d);
      int t = (int)((tp >> (8 * k)) & 255u);
      if (t == n + 1) {
        atomicAdd(&histP[key], 1);
        float sd = (float)((sp >> (8 * k)) & 255u) * (1.0f / 255.0f);
        float df = sd - d;
        sacc += df * df;
      } else {
        atomicAdd(&histN[key], 1);
      }
    }
    if (it < 31) { ee = ne; tp = ntp; sp = nsp; g = ng; }
  }
  for (int off = 32; off > 0; off >>= 1) sacc += __shfl_down(sacc, off, 64);
  if (lane == 0 && sacc != 0.f) atomicAdd(&seedi[seg], sacc);
  __syncthreads();
  size_t pb = (size_t)bid * KTOT;
  for (int k = tid; k < KTOT; k += S1T) {
    partP[pb + k] = (unsigned short)histP[k];
    partN[pb + k] = (unsigned short)histN[k];
  }
}

// ---------------- phase 2+3: combine partials, LDS scans, bucket-sweep Lovasz ----------------
__global__ void __launch_bounds__(1024)
lovasz_kernel(const unsigned short* __restrict__ partP, const unsigned short* __restrict__ partN,
              const float* __restrict__ stats, float* __restrict__ instAcc) {
  __shared__ int histP[KTOT];
  __shared__ int histN[KTOT];
  __shared__ int PreP[KTOT + 1];
  __shared__ int PreN[KTOT + 1];
  __shared__ int scr[1024];
  __shared__ float prm[2];
  int seg = blockIdx.x;
  int tid = threadIdx.x;
  if (tid == 0) {
    Params pp = calc_params(stats + (size_t)seg * 8);
    prm[0] = pp.valid;
    prm[1] = pp.cnt;
  }
  __syncthreads();
  if (prm[0] == 0.f) {
    if (tid == 0) instAcc[seg] = 0.f;
    return;
  }
  int P = (int)prm[1];
  int Nn = HW - P;
  for (int k = tid; k < KTOT; k += 1024) {
    int sp = 0, sn = 0;
#pragma unroll
    for (int s = 0; s < NSPL; ++s) {
      size_t pb = (size_t)(seg * NSPL + s) * KTOT;
      sp += partP[pb + k];
      sn += partN[pb + k];
    }
    histP[k] = sp;
    histN[k] = sn;
  }
  __syncthreads();
  {
    int base = tid * 3;
    int a0 = (base < KTOT) ? histP[base] : 0;
    int a1 = (base + 1 < KTOT) ? histP[base + 1] : 0;
    int a2 = (base + 2 < KTOT) ? histP[base + 2] : 0;
    scr[tid] = a0 + a1 + a2;
    __syncthreads();
    for (int off = 1; off < 1024; off <<= 1) {
      int v = scr[tid];
      int u = (tid >= off) ? scr[tid - off] : 0;
      __syncthreads();
      scr[tid] = v + u;
      __syncthreads();
    }
    int excl = (tid > 0) ? scr[tid - 1] : 0;
    if (base < KTOT) PreP[base] = excl;
    if (base + 1 < KTOT) PreP[base + 1] = excl + a0;
    if (base + 2 < KTOT) PreP[base + 2] = excl + a0 + a1;
    if (tid == 0) PreP[KTOT] = scr[1023];
    __syncthreads();
    a0 = (base < KTOT) ? histN[base] : 0;
    a1 = (base + 1 < KTOT) ? histN[base + 1] : 0;
    a2 = (base + 2 < KTOT) ? histN[base + 2] : 0;
    scr[tid] = a0 + a1 + a2;
    __syncthreads();
    for (int off = 1; off < 1024; off <<= 1) {
      int v = scr[tid];
      int u = (tid >= off) ? scr[tid - off] : 0;
      __syncthreads();
      scr[tid] = v + u;
      __syncthreads();
    }
    excl = (tid > 0) ? scr[tid - 1] : 0;
    if (base < KTOT) PreN[base] = excl;
    if (base + 1 < KTOT) PreN[base + 1] = excl + a0;
    if (base + 2 < KTOT) PreN[base + 2] = excl + a0 + a1;
    if (tid == 0) PreN[KTOT] = scr[1023];
    __syncthreads();
  }
  float acc = 0.f;
  for (int k = tid; k < KTOT; k += 1024) {
    int hp = histP[k], hn = histN[k];
    if ((hp | hn) == 0) continue;
    float lo, hi;
    boundsof(k, &lo, &hi);
    float m = 0.5f * (lo + hi);
    m = fminf(m, __uint_as_float(0x3F7FFFFFu));
    float tv = 1.0f - m;
    int j = keyof(tv);
    float jlo, jhi;
    boundsof(j, &jlo, &jhi);
    float den = jhi - jlo;
    float fr = (den > 0.f) ? (tv - jlo) / den : 0.5f;
    fr = fminf(fmaxf(fr, 0.f), 1.f);
    if (hp) {
      float q = (float)(Nn - PreN[j + 1]) + (1.0f - fr) * (float)histN[j];
      float a = 2.0f - 2.0f * m;
      acc += (float)hp * a / ((float)P + q);
    }
    if (hn) {
      float p = (float)PreP[j] + fr * (float)histP[j];
      int R = Nn - PreN[k + 1];
      float u0 = 1.0f / (float)(P + R);
      float u1 = 1.0f / (float)(P + R + hn);
      acc += (2.0f * m) * ((float)P - p) * (u0 - u1);
    }
  }
  float* scrf = (float*)scr;
  scrf[tid] = acc;
  __syncthreads();
  for (int s = 512; s > 0; s >>= 1) {
    if (tid < s) scrf[tid] += scrf[tid + s];
    __syncthreads();
  }
  if (tid == 0) instAcc[seg] = scrf[0];
}

// ---------------- final combine ----------------
__global__ void final_kernel(const float* __restrict__ stats, const float* __restrict__ instAcc,
                             const float* __restrict__ seediAcc, const float* __restrict__ seedbg,
                             float* __restrict__ out) {
  int b = threadIdx.x;
  __shared__ float red[64];
  float lb = 0.f;
  if (b < BATCH) {
    float sv = 0.f, si = 0.f, svar = 0.f, ssd = 0.f;
    for (int n = 0; n < NID; ++n) {
      Params pp = calc_params(stats + (size_t)(b * NID + n) * 8);
      float vf = pp.valid;
      sv += vf;
      si += vf * instAcc[b * NID + n];
      svar += vf * pp.var;
      ssd += vf * seediAcc[b * NID + n];
    }
    float obj = fmaxf(sv, 1.0f);
    lb = si / obj + 10.0f * (svar / obj) + (seedbg[b] + ssd) / (float)HW;
  }
  red[threadIdx.x] = lb;
  __syncthreads();
  for (int s = 32; s > 0; s >>= 1) {
    if (threadIdx.x < s) red[threadIdx.x] += red[threadIdx.x + s];
    __syncthreads();
  }
  if (threadIdx.x == 0) out[0] = red[0] / (float)BATCH;
}

extern "C" void kernel_launch(void* const* d_in, const int* in_sizes, int n_in,
                              void* d_out, int out_size, void* d_ws, size_t ws_size,
                              hipStream_t stream) {
  const float* pred = (const float*)d_in[0];
  const int* inst = (const int*)d_in[1];
  const int* lab = (const int*)d_in[2];
  float* out = (float*)d_out;

  // head (floats): seediAcc[240] | stats[1920] | instAcc[240] | seedbg[16]
  float* wsf = (float*)d_ws;
  float* seediAcc = wsf;
  float* stats = wsf + 240;
  float* instAcc = wsf + 2160;
  float* seedbg = wsf + 2400;
  char* p = (char*)d_ws + HEADB;
  unsigned* exyh = (unsigned*)p;                 p += (size_t)BATCH * HW * 4;         // 16.78 MB
  unsigned* tb8 = (unsigned*)p;                  p += (size_t)BATCH * HW;             // 4.19 MB
  unsigned* sd8 = (unsigned*)p;                  p += (size_t)BATCH * HW;             // 4.19 MB
  unsigned short* partP = (unsigned short*)p;    p += (size_t)NSEG * NSPL * KTOT * 2; // 4.65 MB
  unsigned short* partN = (unsigned short*)p;    p += (size_t)NSEG * NSPL * KTOT * 2; // 4.65 MB
  float* blockpart = (float*)p;                  // 2048*112*4 = 0.92 MB; total ~35.5 MB

  hipMemsetAsync(seediAcc, 0, 240 * sizeof(float), stream);
  pre_kernel<<<PREBLK, 256, 0, stream>>>(pred, inst, lab, blockpart, exyh, tb8, sd8);
  reduce_kernel<<<dim3(NID * 7 + 1, BATCH), 64, 0, stream>>>(blockpart, stats, seedbg);
  hist_kernel<<<NSEG * NSPL, S1T, 0, stream>>>(exyh, tb8, sd8, stats, partP, partN, seediAcc);
  lovasz_kernel<<<NSEG, 1024, 0, stream>>>(partP, partN, stats, instAcc);
  final_kernel<<<1, 64, 0, stream>>>(stats, instAcc, seediAcc, seedbg, out);
}

// Round 9
// 253.263 us; speedup vs baseline: 1.2879x; 1.2879x over previous
//
#include <hip/hip_runtime.h>
#include <hip/hip_fp16.h>
#include <cmath>

#define BATCH 16
#define NID   15
#define NSEG  240
#define HW    262144          // 512*512
#define HEADB 65536
#define NSPL  8               // pixel splits per seg-chunk in hist
#define NCHK  4               // seg chunks (4+4+4+3)
#define PREBLK 512            // pre blocks (32 per batch, 8192 px each)
#define PSTRIDE 112           // floats per pre-block partial record

// compact key space for d = exp(-arg) in [0,1]
#define KFINEBASE 30208       // 0x3B800000 >> 15
#define KOVF 119
#define KTOT 2424             // 119 + 2305

__device__ __forceinline__ int keyof(float d) {
  unsigned b = __float_as_uint(d);
  return (b >= 0x3B800000u) ? (int)((b >> 15) - KFINEBASE + KOVF) : (int)(b >> 23);
}
__device__ __forceinline__ void boundsof(int k, float* lo, float* hi) {
  if (k >= KOVF) {
    unsigned u = (unsigned)(k - KOVF + KFINEBASE) << 15;
    *lo = __uint_as_float(u);
    *hi = __uint_as_float(u + 32768u);
  } else {
    *lo = __uint_as_float((unsigned)k << 23);
    *hi = __uint_as_float((unsigned)(k + 1) << 23);
  }
}

__device__ __forceinline__ float fast_tanh(float x) {
  float e = __expf(2.0f * x);
  return 1.0f - 2.0f / (e + 1.0f);
}
__device__ __forceinline__ float fast_sigmoid(float x) {
  return 1.0f / (1.0f + __expf(-x));
}

struct Params { float cx, cy, e0, e1, var, valid, cnt; };
__device__ __forceinline__ Params calc_params(const float* __restrict__ st) {
  Params p;
  float cnt = st[0];
  float safe = fmaxf(cnt, 1.0f);
  p.cx = st[1] / safe;
  p.cy = st[2] / safe;
  float m0 = st[3] / safe, m1 = st[4] / safe;
  float v0 = st[5] - 2.0f * m0 * (m0 * safe) + m0 * m0 * cnt;
  float v1 = st[6] - 2.0f * m1 * (m1 * safe) + m1 * m1 * cnt;
  p.var = (v0 + v1) / (2.0f * safe);
  p.e0 = expf(10.0f * m0);
  p.e1 = expf(10.0f * m1);
  p.valid = (cnt > 0.f) ? 1.f : 0.f;
  p.cnt = cnt;
  return p;
}

// ---------------- pre: register-accumulated stats (NO per-pixel LDS/global atomics) ----------------
__global__ void __launch_bounds__(256, 2)
pre_kernel(const float* __restrict__ pred, const int* __restrict__ inst,
           const int* __restrict__ lab, float* __restrict__ blockpart,
           unsigned* __restrict__ exyh, unsigned* __restrict__ tb8,
           unsigned* __restrict__ sd8) {
  __shared__ float ws[4][NID * 7 + 1];
  int tid = threadIdx.x;
  int w = tid >> 6, lane = tid & 63;
  int gid = blockIdx.x;
  int b = gid >> 5, c = gid & 31;      // 32 blocks per batch, 8192 px per block
  const float* pb = pred + (size_t)b * 5 * HW;
  const int4* ip = (const int4*)(inst + (size_t)b * HW);
  const int4* lp = (const int4*)(lab + (size_t)b * HW);
  size_t bq = (size_t)b * (HW / 4);
  float acc[NID][7];
#pragma unroll
  for (int id = 0; id < NID; ++id)
#pragma unroll
    for (int s = 0; s < 7; ++s) acc[id][s] = 0.f;
  float bgacc = 0.f;
  for (int it = 0; it < 8; ++it) {
    int g = c * 2048 + it * 256 + tid;
    float4 v0 = ((const float4*)pb)[g];
    float4 v1 = ((const float4*)(pb + HW))[g];
    float4 v2 = ((const float4*)(pb + 2 * HW))[g];
    float4 v3 = ((const float4*)(pb + 3 * HW))[g];
    float4 v4 = ((const float4*)(pb + 4 * HW))[g];
    int4 t4 = ip[g];
    int4 l4 = lp[g];
    float p0a[4] = {v0.x, v0.y, v0.z, v0.w};
    float p1a[4] = {v1.x, v1.y, v1.z, v1.w};
    float p2a[4] = {v2.x, v2.y, v2.z, v2.w};
    float p3a[4] = {v3.x, v3.y, v3.z, v3.w};
    float p4a[4] = {v4.x, v4.y, v4.z, v4.w};
    int ta[4] = {t4.x, t4.y, t4.z, t4.w};
    int la[4] = {l4.x, l4.y, l4.z, l4.w};
    unsigned eo[4], tpack = 0, spack = 0;
    int px0 = g * 4;
#pragma unroll
    for (int k = 0; k < 4; ++k) {
      int px = px0 + k;
      float xm = (float)(px & 511) * (1.0f / 511.0f);
      float ym = (float)(px >> 9) * (1.0f / 511.0f);
      float ex = fast_tanh(p0a[k]) + xm;
      float ey = fast_tanh(p1a[k]) + ym;
      float sd = fast_sigmoid(p4a[k]);
      __half2 h = __floats2half2_rn(ex, ey);
      eo[k] = *reinterpret_cast<unsigned*>(&h);
      int t = ta[k];
      tpack |= ((unsigned)(t & 255)) << (8 * k);
      unsigned sq = (unsigned)(sd * 255.0f + 0.5f);
      spack |= (sq & 255u) << (8 * k);
      float p2 = p2a[k], p3 = p3a[k];
      float q2 = p2 * p2, q3 = p3 * p3;
#pragma unroll
      for (int id = 0; id < NID; ++id) {
        float pr = (t == id + 1) ? 1.0f : 0.0f;
        acc[id][0] += pr;
        acc[id][1] += pr * ex;
        acc[id][2] += pr * ey;
        acc[id][3] += pr * p2;
        acc[id][4] += pr * p3;
        acc[id][5] += pr * q2;
        acc[id][6] += pr * q3;
      }
      if (la[k] == 0) bgacc += sd * sd;
    }
    ((uint4*)exyh)[bq + g] = make_uint4(eo[0], eo[1], eo[2], eo[3]);
    tb8[bq + g] = tpack;
    sd8[bq + g] = spack;
  }
  // wave shfl reduction of 105 accumulators + bg
#pragma unroll
  for (int id = 0; id < NID; ++id)
#pragma unroll
    for (int s = 0; s < 7; ++s) {
      float v = acc[id][s];
      for (int off = 32; off > 0; off >>= 1) v += __shfl_down(v, off, 64);
      if (lane == 0) ws[w][id * 7 + s] = v;
    }
  for (int off = 32; off > 0; off >>= 1) bgacc += __shfl_down(bgacc, off, 64);
  if (lane == 0) ws[w][NID * 7] = bgacc;
  __syncthreads();
  float* bp = blockpart + (size_t)gid * PSTRIDE;
  for (int i = tid; i < NID * 7 + 1; i += 256)
    bp[i] = ws[0][i] + ws[1][i] + ws[2][i] + ws[3][i];
}

// ---------------- reduce pre partials (32 blocks/batch) -> stats, seedbg ----------------
__global__ void reduce_kernel(const float* __restrict__ blockpart, float* __restrict__ stats,
                              float* __restrict__ seedbg) {
  int s = blockIdx.x;       // 0..105
  int b = blockIdx.y;
  int tid = threadIdx.x;    // 64
  float v = (tid < 32) ? blockpart[(size_t)(b * 32 + tid) * PSTRIDE + s] : 0.f;
  for (int off = 32; off > 0; off >>= 1) v += __shfl_down(v, off, 64);
  if (tid == 0) {
    if (s < NID * 7) {
      int id = s / 7, st = s % 7;
      stats[(b * NID + id) * 8 + st] = v;
    } else {
      seedbg[b] = v;
    }
  }
}

// ---------------- hist: 4 segments per block, packed pos|neg LDS histograms ----------------
__global__ void __launch_bounds__(512)
hist_kernel(const unsigned* __restrict__ exyh, const unsigned* __restrict__ tb8,
            const unsigned* __restrict__ sd8, const float* __restrict__ stats,
            unsigned* __restrict__ partPN, float* __restrict__ seedi) {
  int split = blockIdx.x;       // 0..7
  int chunk = blockIdx.y;       // 0..3
  int b = blockIdx.z;           // 0..15
  int seg0 = chunk * 4;         // first local seg id in chunk (global id seg0..seg0+3, <15)
  __shared__ unsigned lhist[4 * KTOT];
  __shared__ float prm[4][5];   // cx, cy, e0, e1, valid
  int tid = threadIdx.x;
  if (tid < 4) {
    int gs = seg0 + tid;
    if (gs < NID) {
      Params pp = calc_params(stats + (size_t)(b * NID + gs) * 8);
      prm[tid][0] = pp.cx; prm[tid][1] = pp.cy; prm[tid][2] = pp.e0; prm[tid][3] = pp.e1;
      prm[tid][4] = pp.valid;
    } else {
      prm[tid][4] = 0.f;
    }
  }
  for (int k = tid; k < 4 * KTOT; k += 512) lhist[k] = 0u;
  __syncthreads();
  float cxr[4], cyr[4], e0r[4], e1r[4];
  bool vr[4];
#pragma unroll
  for (int n = 0; n < 4; ++n) {
    cxr[n] = prm[n][0]; cyr[n] = prm[n][1]; e0r[n] = prm[n][2]; e1r[n] = prm[n][3];
    vr[n] = (prm[n][4] != 0.f);
  }
  const uint4* ev = (const uint4*)exyh + (size_t)b * (HW / 4);
  const unsigned* tv = tb8 + (size_t)b * (HW / 4);
  const unsigned* sv = sd8 + (size_t)b * (HW / 4);
  int lane = tid & 63;
  int wid = tid >> 6;               // 8 waves
  int swl = (lane * 21) & 63;       // decorrelate bucket keys within a wave
  float sacc[4] = {0.f, 0.f, 0.f, 0.f};
  // groups: 65536/batch; per split 8192; per block 16 iters of 512
  int g = split * 8192 + wid * 64 + swl;
  uint4 ee = ev[g];
  unsigned tp = tv[g];
  unsigned sp = sv[g];
  for (int it = 0; it < 16; ++it) {
    uint4 ne; unsigned ntp, nsp;
    int ng = g + 512;
    if (it < 15) { ne = ev[ng]; ntp = tv[ng]; nsp = sv[ng]; }
    unsigned ew[4] = {ee.x, ee.y, ee.z, ee.w};
#pragma unroll
    for (int k = 0; k < 4; ++k) {
      unsigned u = ew[k];
      __half2 h = *reinterpret_cast<__half2*>(&u);
      float2 e = __half22float2(h);
      int t = (int)((tp >> (8 * k)) & 255u);
#pragma unroll
      for (int n = 0; n < 4; ++n) {
        if (!vr[n]) continue;
        float dx = e.x - cxr[n];
        float dy = e.y - cyr[n];
        float d = __expf(-(e0r[n] * dx * dx + e1r[n] * dy * dy));
        int key = keyof(d);
        bool pos = (t == seg0 + n + 1);
        atomicAdd(&lhist[n * KTOT + key], pos ? 65536u : 1u);
        if (pos) {
          float sd = (float)((sp >> (8 * k)) & 255u) * (1.0f / 255.0f);
          float df = sd - d;
          sacc[n] += df * df;
        }
      }
    }
    if (it < 15) { ee = ne; tp = ntp; sp = nsp; g = ng; }
  }
#pragma unroll
  for (int n = 0; n < 4; ++n) {
    float v = sacc[n];
    for (int off = 32; off > 0; off >>= 1) v += __shfl_down(v, off, 64);
    if (lane == 0 && v != 0.f) atomicAdd(&seedi[b * NID + seg0 + n], v);
  }
  __syncthreads();
#pragma unroll
  for (int n = 0; n < 4; ++n) {
    int gs = seg0 + n;
    if (gs >= NID) break;
    size_t base = ((size_t)(b * NID + gs) * NSPL + split) * KTOT;
    for (int k = tid; k < KTOT; k += 512) partPN[base + k] = lhist[n * KTOT + k];
  }
}

// ---------------- lovasz: combine packed partials, LDS scans, bucket-sweep ----------------
__global__ void __launch_bounds__(1024)
lovasz_kernel(const unsigned* __restrict__ partPN, const float* __restrict__ stats,
              float* __restrict__ instAcc) {
  __shared__ int histP[KTOT];
  __shared__ int histN[KTOT];
  __shared__ int PreP[KTOT + 1];
  __shared__ int PreN[KTOT + 1];
  __shared__ int scr[1024];
  __shared__ float prm[2];
  int seg = blockIdx.x;
  int tid = threadIdx.x;
  if (tid == 0) {
    Params pp = calc_params(stats + (size_t)seg * 8);
    prm[0] = pp.valid;
    prm[1] = pp.cnt;
  }
  __syncthreads();
  if (prm[0] == 0.f) {
    if (tid == 0) instAcc[seg] = 0.f;
    return;
  }
  int P = (int)prm[1];
  int Nn = HW - P;
  for (int k = tid; k < KTOT; k += 1024) {
    int sp = 0, sn = 0;
#pragma unroll
    for (int s = 0; s < NSPL; ++s) {
      unsigned v = partPN[((size_t)seg * NSPL + s) * KTOT + k];
      sp += (int)(v >> 16);
      sn += (int)(v & 0xFFFFu);
    }
    histP[k] = sp;
    histN[k] = sn;
  }
  __syncthreads();
  {
    int base = tid * 3;
    int a0 = (base < KTOT) ? histP[base] : 0;
    int a1 = (base + 1 < KTOT) ? histP[base + 1] : 0;
    int a2 = (base + 2 < KTOT) ? histP[base + 2] : 0;
    scr[tid] = a0 + a1 + a2;
    __syncthreads();
    for (int off = 1; off < 1024; off <<= 1) {
      int v = scr[tid];
      int u = (tid >= off) ? scr[tid - off] : 0;
      __syncthreads();
      scr[tid] = v + u;
      __syncthreads();
    }
    int excl = (tid > 0) ? scr[tid - 1] : 0;
    if (base < KTOT) PreP[base] = excl;
    if (base + 1 < KTOT) PreP[base + 1] = excl + a0;
    if (base + 2 < KTOT) PreP[base + 2] = excl + a0 + a1;
    if (tid == 0) PreP[KTOT] = scr[1023];
    __syncthreads();
    a0 = (base < KTOT) ? histN[base] : 0;
    a1 = (base + 1 < KTOT) ? histN[base + 1] : 0;
    a2 = (base + 2 < KTOT) ? histN[base + 2] : 0;
    scr[tid] = a0 + a1 + a2;
    __syncthreads();
    for (int off = 1; off < 1024; off <<= 1) {
      int v = scr[tid];
      int u = (tid >= off) ? scr[tid - off] : 0;
      __syncthreads();
      scr[tid] = v + u;
      __syncthreads();
    }
    excl = (tid > 0) ? scr[tid - 1] : 0;
    if (base < KTOT) PreN[base] = excl;
    if (base + 1 < KTOT) PreN[base + 1] = excl + a0;
    if (base + 2 < KTOT) PreN[base + 2] = excl + a0 + a1;
    if (tid == 0) PreN[KTOT] = scr[1023];
    __syncthreads();
  }
  float acc = 0.f;
  for (int k = tid; k < KTOT; k += 1024) {
    int hp = histP[k], hn = histN[k];
    if ((hp | hn) == 0) continue;
    float lo, hi;
    boundsof(k, &lo, &hi);
    float m = 0.5f * (lo + hi);
    m = fminf(m, __uint_as_float(0x3F7FFFFFu));
    float tv = 1.0f - m;
    int j = keyof(tv);
    float jlo, jhi;
    boundsof(j, &jlo, &jhi);
    float den = jhi - jlo;
    float fr = (den > 0.f) ? (tv - jlo) / den : 0.5f;
    fr = fminf(fmaxf(fr, 0.f), 1.f);
    if (hp) {
      float q = (float)(Nn - PreN[j + 1]) + (1.0f - fr) * (float)histN[j];
      float a = 2.0f - 2.0f * m;
      acc += (float)hp * a / ((float)P + q);
    }
    if (hn) {
      float p = (float)PreP[j] + fr * (float)histP[j];
      int R = Nn - PreN[k + 1];
      float u0 = 1.0f / (float)(P + R);
      float u1 = 1.0f / (float)(P + R + hn);
      acc += (2.0f * m) * ((float)P - p) * (u0 - u1);
    }
  }
  float* scrf = (float*)scr;
  scrf[tid] = acc;
  __syncthreads();
  for (int s = 512; s > 0; s >>= 1) {
    if (tid < s) scrf[tid] += scrf[tid + s];
    __syncthreads();
  }
  if (tid == 0) instAcc[seg] = scrf[0];
}

// ---------------- final combine ----------------
__global__ void final_kernel(const float* __restrict__ stats, const float* __restrict__ instAcc,
                             const float* __restrict__ seediAcc, const float* __restrict__ seedbg,
                             float* __restrict__ out) {
  int b = threadIdx.x;
  __shared__ float red[64];
  float lb = 0.f;
  if (b < BATCH) {
    float sv = 0.f, si = 0.f, svar = 0.f, ssd = 0.f;
    for (int n = 0; n < NID; ++n) {
      Params pp = calc_params(stats + (size_t)(b * NID + n) * 8);
      float vf = pp.valid;
      sv += vf;
      si += vf * instAcc[b * NID + n];
      svar += vf * pp.var;
      ssd += vf * seediAcc[b * NID + n];
    }
    float obj = fmaxf(sv, 1.0f);
    lb = si / obj + 10.0f * (svar / obj) + (seedbg[b] + ssd) / (float)HW;
  }
  red[threadIdx.x] = lb;
  __syncthreads();
  for (int s = 32; s > 0; s >>= 1) {
    if (threadIdx.x < s) red[threadIdx.x] += red[threadIdx.x + s];
    __syncthreads();
  }
  if (threadIdx.x == 0) out[0] = red[0] / (float)BATCH;
}

extern "C" void kernel_launch(void* const* d_in, const int* in_sizes, int n_in,
                              void* d_out, int out_size, void* d_ws, size_t ws_size,
                              hipStream_t stream) {
  const float* pred = (const float*)d_in[0];
  const int* inst = (const int*)d_in[1];
  const int* lab = (const int*)d_in[2];
  float* out = (float*)d_out;

  // head (floats): seediAcc[240] | stats[1920] | instAcc[240] | seedbg[16]
  float* wsf = (float*)d_ws;
  float* seediAcc = wsf;
  float* stats = wsf + 240;
  float* instAcc = wsf + 2160;
  float* seedbg = wsf + 2400;
  char* p = (char*)d_ws + HEADB;
  unsigned* exyh = (unsigned*)p;            p += (size_t)BATCH * HW * 4;          // 16.78 MB
  unsigned* tb8 = (unsigned*)p;             p += (size_t)BATCH * HW;              // 4.19 MB
  unsigned* sd8 = (unsigned*)p;             p += (size_t)BATCH * HW;              // 4.19 MB
  unsigned* partPN = (unsigned*)p;          p += (size_t)NSEG * NSPL * KTOT * 4;  // 18.62 MB
  float* blockpart = (float*)p;             // 512*112*4 = 0.23 MB; total ~44.1 MB

  hipMemsetAsync(seediAcc, 0, 240 * sizeof(float), stream);
  pre_kernel<<<PREBLK, 256, 0, stream>>>(pred, inst, lab, blockpart, exyh, tb8, sd8);
  reduce_kernel<<<dim3(NID * 7 + 1, BATCH), 64, 0, stream>>>(blockpart, stats, seedbg);
  hist_kernel<<<dim3(NSPL, NCHK, BATCH), 512, 0, stream>>>(exyh, tb8, sd8, stats, partPN, seediAcc);
  lovasz_kernel<<<NSEG, 1024, 0, stream>>>(partPN, stats, instAcc);
  final_kernel<<<1, 64, 0, stream>>>(stats, instAcc, seediAcc, seedbg, out);
}